// Round 2
// baseline (21324.458 us; speedup 1.0000x reference)
//
#include <hip/hip_runtime.h>
#include <hip/hip_bf16.h>
#include <math.h>

typedef __hip_bfloat16 bf16;

#define D_   1024
#define DE_  4096
#define H_   16
#define CHD_ 32
#define MHD_ 64
#define L_   6
#define B_   2
#define T_   1024
#define M_   (B_*T_)   // 2048
#define V_   32000
#define EPS_ 1e-5f

// flexible load: f16=1 -> buffer is bf16, else fp32
__device__ __forceinline__ float ldf(const void* p, size_t i, int f16){
    return f16 ? __bfloat162float(((const bf16*)p)[i])
               : ((const float*)p)[i];
}
__device__ __forceinline__ float sigf(float x){ return 1.f / (1.f + __expf(-x)); }

// ---------------- dtype detection: bf16 weights have small exponents ----------
__global__ void detect_dtype(const unsigned short* __restrict__ te_u16, int* __restrict__ flag){
    __shared__ int any_big;
    if (threadIdx.x == 0) any_big = 0;
    __syncthreads();
    int big = 0;
    #pragma unroll
    for (int i=0;i<4;i++){
        unsigned short u = te_u16[threadIdx.x + 256*i];
        int e = (u >> 7) & 0xFF;          // bf16 exponent field
        if (e >= 0x88) big = 1;           // |v| >= 512: impossible for real weights
    }
    if (big) any_big = 1;                 // benign race, same value
    __syncthreads();
    if (threadIdx.x == 0) *flag = any_big ? 0 : 1;   // garbage found -> fp32
}

// ---------------- embedding: x[m,d] = te[ids[m],d] + pe[m%T,d] ----------------
__global__ void embed_kernel(const int* __restrict__ ids, const void* __restrict__ te,
                             const void* __restrict__ pe, float* __restrict__ x,
                             const int* __restrict__ flagp){
    int f16 = *flagp;
    int idx = blockIdx.x*256 + threadIdx.x;      // over M_*D_
    int m = idx >> 10, d = idx & 1023;
    int t = m & (T_-1);
    x[idx] = ldf(te, (size_t)ids[m]*D_ + d, f16) + ldf(pe, (size_t)t*D_ + d, f16);
}

// ---------------- layernorm (row-per-block, 256 threads, D=1024) ----------------
__device__ __forceinline__ float blk_sum(float v, float* smem){
    #pragma unroll
    for (int o=32;o>0;o>>=1) v += __shfl_xor(v, o);   // xor butterfly: all in-range
    __syncthreads();
    if ((threadIdx.x & 63) == 0) smem[threadIdx.x>>6] = v;
    __syncthreads();
    return smem[0]+smem[1]+smem[2]+smem[3];
}

__global__ void ln_kernel(const float* __restrict__ x, const void* __restrict__ g,
                          const void* __restrict__ b, size_t goff,
                          float* __restrict__ out, const int* __restrict__ flagp){
    __shared__ float smem[4];
    int f16 = *flagp;
    int row = blockIdx.x, tid = threadIdx.x;
    const float* xr = x + (size_t)row*D_;
    float v[4]; float s = 0.f;
    #pragma unroll
    for (int i=0;i<4;i++){ v[i] = xr[tid+256*i]; s += v[i]; }
    float mean = blk_sum(s, smem) * (1.f/D_);
    float vs = 0.f;
    #pragma unroll
    for (int i=0;i<4;i++){ float d = v[i]-mean; vs += d*d; }
    float inv = rsqrtf(blk_sum(vs, smem)*(1.f/D_) + EPS_);
    float* orow = out + (size_t)row*D_;
    #pragma unroll
    for (int i=0;i<4;i++){
        int c = tid+256*i;
        orow[c] = (v[i]-mean)*inv*ldf(g, goff+c, f16) + ldf(b, goff+c, f16);
    }
}

// ---------------- GEMM NN ------------------------------------------------------
// C[M,N] = A[M,K] @ W[K,N] + bias, then:
//   MODE 0: store (or += if RESID)    MODE 1: silu, store
//   MODE 2: s = sigmoid(val); C = silu(C * s)   (in-place gated activation)
// A,C fp32; W,bias flagged dtype. 64x64 tile, BK=16, 256 thr, 4x4/thread.
template<int MODE, bool RESID>
__global__ void gemm_nn(const float* __restrict__ A, const void* __restrict__ W,
                        const void* __restrict__ bias, size_t woff, size_t boff,
                        float* __restrict__ C, int N, int K,
                        const int* __restrict__ flagp){
    __shared__ float As[16][65];   // +1 pad: avoids bank conflicts
    __shared__ float Ws[16][65];
    int f16 = *flagp;
    int tid = threadIdx.x;
    int m0 = blockIdx.y*64, n0 = blockIdx.x*64;
    int lk = tid & 15, lr = tid >> 4;    // A-tile load coords
    int lnn = tid & 63, lkr = tid >> 6;  // W-tile load coords
    int tx = tid & 15, ty = tid >> 4;
    float acc[4][4] = {};
    for (int k0=0;k0<K;k0+=16){
        #pragma unroll
        for (int i=0;i<4;i++)
            As[lk][lr+16*i] = A[(size_t)(m0+lr+16*i)*K + k0 + lk];
        #pragma unroll
        for (int i=0;i<4;i++){
            int kr = lkr + 4*i;
            Ws[kr][lnn] = ldf(W, woff + (size_t)(k0+kr)*N + n0 + lnn, f16);
        }
        __syncthreads();
        #pragma unroll
        for (int kk=0;kk<16;kk++){
            float a[4], w[4];
            #pragma unroll
            for (int i=0;i<4;i++) a[i] = As[kk][ty*4+i];
            #pragma unroll
            for (int j=0;j<4;j++) w[j] = Ws[kk][tx*4+j];
            #pragma unroll
            for (int i=0;i<4;i++)
                #pragma unroll
                for (int j=0;j<4;j++)
                    acc[i][j] += a[i]*w[j];
        }
        __syncthreads();
    }
    #pragma unroll
    for (int i=0;i<4;i++){
        int mr = m0 + ty*4 + i;
        float* crow = C + (size_t)mr*N;
        #pragma unroll
        for (int j=0;j<4;j++){
            int nc = n0 + tx*4 + j;
            float val = acc[i][j] + ldf(bias, boff + nc, f16);
            if (MODE == 1) val = val * sigf(val);                       // silu
            if (MODE == 2){
                float s = sigf(val);
                float z = crow[nc] * s;
                crow[nc] = z * sigf(z);                                 // silu(e*g)
            } else if (RESID) crow[nc] += val;
            else crow[nc] = val;
        }
    }
}

// ---------------- tied head: C[M,V] = A[M,K] @ te[V,K]^T, flagged out dtype ----
__global__ void gemm_nt_head(const float* __restrict__ A, const void* __restrict__ Wt,
                             void* __restrict__ C, int N, int K,
                             const int* __restrict__ flagp){
    __shared__ float As[16][65];
    __shared__ float Ws[16][65];
    int f16 = *flagp;
    int tid = threadIdx.x;
    int m0 = blockIdx.y*64, n0 = blockIdx.x*64;
    int lk = tid & 15, lr = tid >> 4;
    int tx = tid & 15, ty = tid >> 4;
    float acc[4][4] = {};
    for (int k0=0;k0<K;k0+=16){
        #pragma unroll
        for (int i=0;i<4;i++)
            As[lk][lr+16*i] = A[(size_t)(m0+lr+16*i)*K + k0 + lk];
        #pragma unroll
        for (int i=0;i<4;i++)
            Ws[lk][lr+16*i] = ldf(Wt, (size_t)(n0+lr+16*i)*K + k0 + lk, f16);
        __syncthreads();
        #pragma unroll
        for (int kk=0;kk<16;kk++){
            float a[4], w[4];
            #pragma unroll
            for (int i=0;i<4;i++) a[i] = As[kk][ty*4+i];
            #pragma unroll
            for (int j=0;j<4;j++) w[j] = Ws[kk][tx*4+j];
            #pragma unroll
            for (int i=0;i<4;i++)
                #pragma unroll
                for (int j=0;j<4;j++)
                    acc[i][j] += a[i]*w[j];
        }
        __syncthreads();
    }
    #pragma unroll
    for (int i=0;i<4;i++){
        size_t mr = m0 + ty*4 + i;
        #pragma unroll
        for (int j=0;j<4;j++){
            size_t idx = mr*N + n0 + tx*4 + j;
            if (f16) ((bf16*)C)[idx] = __float2bfloat16(acc[i][j]);
            else     ((float*)C)[idx] = acc[i][j];
        }
    }
}

// ---------------- causal attention, online softmax, one wave per (b,h,q) --------
__global__ void attn_kernel(const float* __restrict__ q, const float* __restrict__ k,
                            const float* __restrict__ v, float* __restrict__ y){
    int qi = blockIdx.x, h = blockIdx.y, b = blockIdx.z;
    int tid = threadIdx.x;                      // 64 threads = 1 wave
    __shared__ float qs[CHD_];
    __shared__ float ps[64];
    const float* qrow = q + (size_t)(b*T_+qi)*(H_*CHD_) + h*CHD_;
    if (tid < CHD_) qs[tid] = qrow[tid];
    __syncthreads();
    const float scale = 0.17677669529663687f;   // 1/sqrt(32)
    float acc = 0.f, mrun = -INFINITY, lrun = 0.f;
    for (int j0 = 0; j0 <= qi; j0 += 64){
        int j = j0 + tid;
        bool valid = (j <= qi);
        float s = -3.0e38f;
        if (valid){
            const float* kr = k + (size_t)(b*T_+j)*(H_*CHD_) + h*CHD_;
            float d = 0.f;
            #pragma unroll
            for (int c=0;c<CHD_;c++) d += qs[c]*kr[c];
            s = d * scale;
        }
        float cm = s;
        #pragma unroll
        for (int o=32;o>0;o>>=1) cm = fmaxf(cm, __shfl_xor(cm, o));
        float mnew = fmaxf(mrun, cm);
        float p = valid ? __expf(s - mnew) : 0.f;
        float alpha = (mrun == -INFINITY) ? 0.f : __expf(mrun - mnew);
        float psum = p;
        #pragma unroll
        for (int o=32;o>0;o>>=1) psum += __shfl_xor(psum, o);
        lrun = lrun*alpha + psum;
        acc  = acc*alpha;
        mrun = mnew;
        __syncthreads();
        ps[tid] = p;
        __syncthreads();
        const float* vb = v + (size_t)(b*T_+j0)*(H_*MHD_) + h*MHD_ + tid;
        int jmax = min(64, qi - j0 + 1);
        for (int jj=0; jj<jmax; jj++)
            acc += ps[jj] * vb[(size_t)jj*(H_*MHD_)];
    }
    y[(size_t)(b*T_+qi)*(H_*MHD_) + h*MHD_ + tid] = acc / lrun;
}

extern "C" void kernel_launch(void* const* d_in, const int* in_sizes, int n_in,
                              void* d_out, int out_size, void* d_ws, size_t ws_size,
                              hipStream_t stream){
    const int*  ids   = (const int*) d_in[0];
    const void* te    = d_in[1];
    const void* pe    = d_in[2];
    const void* ln1_g = d_in[3];
    const void* ln1_b = d_in[4];
    const void* qp_w  = d_in[5];
    const void* qp_b  = d_in[6];
    const void* kp_w  = d_in[7];
    const void* kp_b  = d_in[8];
    const void* vp_w  = d_in[9];
    const void* vp_b  = d_in[10];
    const void* out_w = d_in[11];
    const void* out_b = d_in[12];
    const void* ln2_g = d_in[13];
    const void* ln2_b = d_in[14];
    const void* exp_w = d_in[15];
    const void* exp_b = d_in[16];
    const void* gate_w= d_in[17];
    const void* gate_b= d_in[18];
    const void* gup_w = d_in[19];
    const void* gup_b = d_in[20];
    const void* comp_w= d_in[21];
    const void* comp_b= d_in[22];
    const void* lnf_g = d_in[23];
    const void* lnf_b = d_in[24];

    char* ws = (char*)d_ws;
    int*   flag = (int*)(ws);                       // 1 MB region for flag
    float* x   = (float*)(ws + ( 1u<<20));          //  8 MB  [M,1024]
    float* hb  = (float*)(ws + ( 9u<<20));          //  8 MB  [M,1024]
    float* qb  = (float*)(ws + (17u<<20));          //  4 MB  [M,512]   (attn phase)
    float* kb  = (float*)(ws + (21u<<20));          //  4 MB  [M,512]
    float* vb  = (float*)(ws + (25u<<20));          //  8 MB  [M,1024]
    float* yb  = (float*)(ws + (33u<<20));          //  8 MB  [M,1024]  (ends 41 MB)
    float* eb  = (float*)(ws + (17u<<20));          // 32 MB  [M,4096]  (ffn phase, reuses attn region)
    float* g1  = (float*)(ws + (49u<<20));          //  4 MB  [M,1024]  (ends 53 MB)

    detect_dtype<<<1, 256, 0, stream>>>((const unsigned short*)te, flag);
    embed_kernel<<<M_*D_/256, 256, 0, stream>>>(ids, te, pe, x, flag);

    for (int l=0; l<L_; l++){
        size_t lD = (size_t)l*D_;
        ln_kernel<<<M_, 256, 0, stream>>>(x, ln1_g, ln1_b, lD, hb, flag);
        gemm_nn<0,false><<<dim3(8,32), 256, 0, stream>>>(hb, qp_w, qp_b, (size_t)l*D_*512, (size_t)l*512, qb, 512, D_, flag);
        gemm_nn<0,false><<<dim3(8,32), 256, 0, stream>>>(hb, kp_w, kp_b, (size_t)l*D_*512, (size_t)l*512, kb, 512, D_, flag);
        gemm_nn<0,false><<<dim3(16,32),256, 0, stream>>>(hb, vp_w, vp_b, (size_t)l*D_*1024, (size_t)l*1024, vb, 1024, D_, flag);
        attn_kernel<<<dim3(T_,H_,B_), 64, 0, stream>>>(qb, kb, vb, yb);
        gemm_nn<0,true ><<<dim3(16,32),256, 0, stream>>>(yb, out_w, out_b, (size_t)l*1024*1024, (size_t)l*1024, x, 1024, 1024, flag);

        ln_kernel<<<M_, 256, 0, stream>>>(x, ln2_g, ln2_b, lD, hb, flag);
        gemm_nn<0,false><<<dim3(64,32),256, 0, stream>>>(hb, exp_w, exp_b, (size_t)l*D_*DE_, (size_t)l*DE_, eb, DE_, D_, flag);
        gemm_nn<1,false><<<dim3(16,32),256, 0, stream>>>(hb, gate_w, gate_b, (size_t)l*D_*1024, (size_t)l*1024, g1, 1024, D_, flag);
        gemm_nn<2,false><<<dim3(64,32),256, 0, stream>>>(g1, gup_w, gup_b, (size_t)l*1024*DE_, (size_t)l*DE_, eb, DE_, 1024, flag);
        gemm_nn<0,true ><<<dim3(16,32),256, 0, stream>>>(eb, comp_w, comp_b, (size_t)l*DE_*1024, (size_t)l*1024, x, 1024, DE_, flag);
    }

    ln_kernel<<<M_, 256, 0, stream>>>(x, lnf_g, lnf_b, 0, hb, flag);
    gemm_nt_head<<<dim3(V_/64, M_/64), 256, 0, stream>>>(hb, te, d_out, V_, D_, flag);
}